// Round 6
// baseline (427.197 us; speedup 1.0000x reference)
//
#include <hip/hip_runtime.h>
#include <hip/hip_bf16.h>
#include <stdint.h>

#define DIM 256
#define GRID_G 5
#define KTOT 2560                 // 256 * 5 * 2
#define BM 256
#define BN 256
#define BK 64
#define NTHREADS 512
#define AS_BYTES (BM * BK * 2)    // 32 KB per buffer

typedef float f32x4 __attribute__((ext_vector_type(4)));
typedef short bf16x8 __attribute__((ext_vector_type(8)));

static __device__ __forceinline__ uint32_t f2bf_bits(float v) {
    uint32_t u = __float_as_uint(v);
    return (u + 0x7FFFu + ((u >> 16) & 1u)) >> 16;
}

// ---- W pre-transform: Wb[o][k] bf16, k = g*512 + 2*d + s ----
// source fourier_weight layout: [s][o][d][g], flat ((s*256+o)*256+d)*5+g
__global__ void wtransform(const float* __restrict__ W, uint16_t* __restrict__ Wb) {
    int t = blockIdx.x * blockDim.x + threadIdx.x;
    if (t >= DIM * KTOT / 8) return;
    int o  = t / (KTOT / 8);
    int k8 = t - o * (KTOT / 8);
    int k0 = k8 * 8;
    int g  = k0 >> 9;
    int r  = k0 & 511;
    int d0 = r >> 1;
    union { uint16_t v[8]; uint4 q; } u;
#pragma unroll
    for (int j = 0; j < 8; ++j) {
        int d = d0 + (j >> 1);
        int s = j & 1;
        float w = W[(((s * DIM + o) * DIM + d) * GRID_G) + g];
        u.v[j] = (uint16_t)f2bf_bits(w);
    }
    *(uint4*)((char*)Wb + (size_t)t * 16) = u.q;
}

// ---- fused feature+GEMM: 512 thr, BM=256 x BN=256, wave tile 128x64 ----
// A in LDS (dbuf, XOR swizzle); B reg-double-buffered 1 chunk ahead;
// x reg-double-buffered per dr-slab (xqA even dr, xqB odd dr);
// raw s_barrier + lgkmcnt(0)-only drain -> vmem prefetch spans barriers.
__global__ __launch_bounds__(NTHREADS, 1)
void fourier_gemm(const float* __restrict__ x, const uint16_t* __restrict__ Wb,
                  const float* __restrict__ bias, float* __restrict__ out) {
    __shared__ __align__(16) char As[2 * AS_BYTES];   // 64 KB

    const int tid  = threadIdx.x;
    const int lane = tid & 63;
    const int wave = tid >> 6;
    const int wrow = wave >> 2;     // 0..1 (128-row halves)
    const int wcol = wave & 3;      // 0..3 (64-col quarters)
    const int row0 = blockIdx.x * BM;
    const int q16  = (lane >> 4) << 4;
    const int l15  = lane & 15;
    const int sd2  = tid & 15;      // d-pair index within 32-d slab
    const int sn   = tid >> 4;      // 0..31; staged rows n = sn + i*32

    f32x4 acc[8][4];
#pragma unroll
    for (int m = 0; m < 8; ++m)
#pragma unroll
        for (int n = 0; n < 4; ++n)
            acc[m][n] = (f32x4){0.f, 0.f, 0.f, 0.f};

    float2 xqA[8], xqB[8];          // x slabs: even-dr / odd-dr
    bf16x8 bfA[8], bfB[8];          // B fragments, reg double-buffer

#define ISSUE_B(c_, B_)                                                       \
    {                                                                         \
        _Pragma("unroll")                                                     \
        for (int ks = 0; ks < 2; ++ks)                                        \
        _Pragma("unroll")                                                     \
        for (int nf = 0; nf < 4; ++nf) {                                      \
            int o = wcol * 64 + nf * 16 + l15;                                \
            B_[ks * 4 + nf] = *(const bf16x8*)((const char*)Wb +              \
                (size_t)o * (KTOT * 2) + (c_) * 128 + ks * 64 + q16);         \
        }                                                                     \
    }

#define LOAD_X(dr_, XQ_)                                                     \
    {                                                                        \
        _Pragma("unroll")                                                    \
        for (int i = 0; i < 8; ++i) {                                        \
            int n = sn + i * 32;                                             \
            XQ_[i] = *(const float2*)&x[(size_t)(row0 + n) * DIM +           \
                                        (dr_) * 32 + 2 * sd2];               \
        }                                                                    \
    }

#define TRIG_WRITE(kg1, XQ_, abase_)                                          \
    {                                                                         \
        float kgrev = (float)(kg1) * 0.15915494309189535f;                    \
        char* abase = (abase_);                                               \
        _Pragma("unroll")                                                     \
        for (int i = 0; i < 8; ++i) {                                         \
            int n = sn + i * 32;                                              \
            float r0 = XQ_[i].x * kgrev;                                      \
            float r1 = XQ_[i].y * kgrev;                                      \
            float s0, c0, s1, c1;                                             \
            asm("v_sin_f32 %0, %1" : "=v"(s0) : "v"(r0));                     \
            asm("v_cos_f32 %0, %1" : "=v"(c0) : "v"(r0));                     \
            asm("v_sin_f32 %0, %1" : "=v"(s1) : "v"(r1));                     \
            asm("v_cos_f32 %0, %1" : "=v"(c1) : "v"(r1));                     \
            uint32_t p0, p1;                                                  \
            asm("v_cvt_pk_bf16_f32 %0, %1, %2" : "=v"(p0) : "v"(c0), "v"(s0));\
            asm("v_cvt_pk_bf16_f32 %0, %1, %2" : "=v"(p1) : "v"(c1), "v"(s1));\
            int boff = (n * 128 + sd2 * 8) ^ ((n & 7) << 4);                  \
            uint64_t pk = ((uint64_t)p1 << 32) | (uint64_t)p0;                \
            *(uint64_t*)(abase + boff) = pk;                                  \
        }                                                                     \
    }

#define MFMA_KS(ks_, Ac_, B_)                                                 \
    {                                                                         \
        bf16x8 af[8];                                                         \
        _Pragma("unroll")                                                     \
        for (int m = 0; m < 8; ++m) {                                         \
            int rr  = wrow * 128 + m * 16 + l15;                              \
            int off = (rr * 128 + (ks_) * 64 + q16) ^ ((rr & 7) << 4);        \
            af[m] = *(const bf16x8*)((Ac_) + off);                            \
        }                                                                     \
        __builtin_amdgcn_s_setprio(1);                                        \
        _Pragma("unroll")                                                     \
        for (int m = 0; m < 8; ++m)                                           \
        _Pragma("unroll")                                                     \
        for (int nf = 0; nf < 4; ++nf)                                        \
            acc[m][nf] = __builtin_amdgcn_mfma_f32_16x16x32_bf16(             \
                af[m], B_[(ks_) * 4 + nf], acc[m][nf], 0, 0, 0);              \
        __builtin_amdgcn_s_setprio(0);                                        \
    }

    // CHUNK: one BK=64 k-chunk. Reads A from ACUR_/B from BCUR_; prefetches
    // next chunk's B into BNXT_; produces next A tile (kg=kgn_, slab XQ_)
    // into ANXT_. Only lgkm drained at the barrier (vmem spans it).
#define CHUNK(ccur_, cnxt_, BCUR_, BNXT_, ACUR_, ANXT_, kgn_, XQ_, doiss_, dotrig_) \
    {                                                                         \
        if (doiss_) { ISSUE_B(cnxt_, BNXT_); }                                \
        MFMA_KS(0, ACUR_, BCUR_);                                             \
        if (dotrig_) { TRIG_WRITE(kgn_, XQ_, ANXT_); }                        \
        MFMA_KS(1, ACUR_, BCUR_);                                             \
        asm volatile("s_waitcnt lgkmcnt(0)" ::: "memory");                    \
        __builtin_amdgcn_s_barrier();                                         \
        __builtin_amdgcn_sched_barrier(0);                                    \
    }

    char* buf0 = (char*)As;
    char* buf1 = (char*)As + AS_BYTES;

    // ---- prologue: B(chunk 0), x(dr=0)->xqA, A-tile(dr=0,g=0) -> buf0
    ISSUE_B(0, bfA);
    LOAD_X(0, xqA);
    TRIG_WRITE(1, xqA, buf0);
    asm volatile("s_waitcnt lgkmcnt(0)" ::: "memory");
    __builtin_amdgcn_s_barrier();
    __builtin_amdgcn_sched_barrier(0);

    for (int dr2 = 0; dr2 < 4; ++dr2) {
        const int drA = 2 * dr2;
        const int drB = 2 * dr2 + 1;
        const bool more = (dr2 < 3);

        // chunk index in Wb is c = g*8 + dr; tile for NEXT chunk is produced
        // during the current one. x slab for drA lives in xqA, drB in xqB.
        /* j=0 g0 */ CHUNK(drA,       8 + drA,  bfA, bfB, buf0, buf1, 2, xqA, true, true);
        /* j=1 g1 */ CHUNK(8 + drA,  16 + drA,  bfB, bfA, buf1, buf0, 3, xqA, true, true);
        /* j=2 g2 */ CHUNK(16 + drA, 24 + drA,  bfA, bfB, buf0, buf1, 4, xqA, true, true);
        /* j=3 g3 */ LOAD_X(drB, xqB);          // fills the OTHER slab buffer
                     CHUNK(24 + drA, 32 + drA,  bfB, bfA, buf1, buf0, 5, xqA, true, true);
        /* j=4 g4 */ CHUNK(32 + drA, drB,       bfA, bfB, buf0, buf1, 1, xqB, true, true);
        /* j=5 g0 */ CHUNK(drB,       8 + drB,  bfB, bfA, buf1, buf0, 2, xqB, true, true);
        /* j=6 g1 */ CHUNK(8 + drB,  16 + drB,  bfA, bfB, buf0, buf1, 3, xqB, true, true);
        /* j=7 g2 */ CHUNK(16 + drB, 24 + drB,  bfB, bfA, buf1, buf0, 4, xqB, true, true);
        /* j=8 g3 */ if (more) { LOAD_X(drA + 2, xqA); }   // other slab again
                     CHUNK(24 + drB, 32 + drB,  bfA, bfB, buf0, buf1, 5, xqB, true, true);
        /* j=9 g4 */ CHUNK(32 + drB, drB + 1,   bfB, bfA, buf1, buf0, 1, xqA, more, more);
    }

    // ---- epilogue: C/D layout col = lane&15, row = (lane>>4)*4 + reg
#pragma unroll
    for (int nf = 0; nf < 4; ++nf) {
        int ocol = wcol * 64 + nf * 16 + l15;
        float b = bias[ocol];
#pragma unroll
        for (int m = 0; m < 8; ++m) {
            int rbase = row0 + wrow * 128 + m * 16 + ((lane >> 4) << 2);
#pragma unroll
            for (int r2 = 0; r2 < 4; ++r2) {
                out[(size_t)(rbase + r2) * DIM + ocol] = acc[m][nf][r2] + b;
            }
        }
    }

#undef ISSUE_B
#undef LOAD_X
#undef TRIG_WRITE
#undef MFMA_KS
#undef CHUNK
}

extern "C" void kernel_launch(void* const* d_in, const int* in_sizes, int n_in,
                              void* d_out, int out_size, void* d_ws, size_t ws_size,
                              hipStream_t stream) {
    const float* x    = (const float*)d_in[0];
    const float* W    = (const float*)d_in[1];
    const float* bias = (const float*)d_in[2];
    float* out        = (float*)d_out;
    uint16_t* Wb      = (uint16_t*)d_ws;   // 256*2560*2 = 1.28 MB

    int rows = in_sizes[0] / DIM;          // 65536
    int wthreads = DIM * KTOT / 8;         // 81920

    hipLaunchKernelGGL(wtransform, dim3((wthreads + 255) / 256), dim3(256), 0, stream, W, Wb);
    hipLaunchKernelGGL(fourier_gemm, dim3(rows / BM), dim3(NTHREADS), 0, stream,
                       x, Wb, bias, out);
}